// Round 11
// baseline (408.846 us; speedup 1.0000x reference)
//
#include <hip/hip_runtime.h>
#include <hip/hip_cooperative_groups.h>
#include <math.h>

namespace cg = cooperative_groups;

// GAT multi-head attention conv, MI355X. Round 11: single cooperative kernel.
// Phase A: [s2v-role: cursor clear + va=W@a + s-dots] || [mm-role: bf16 MFMA h]
// grid.sync()  Phase B: edge scatter (16B entries).  grid.sync()  Phase C: gather.
// Fallback to the proven round-10 4-kernel path if cooperative launch fails.
constexpr int N_SRC_ = 50000;
constexpr int N_DST_ = 50000;
constexpr int N_TOT_ = 100000;   // s rows: src [0,50000), dst [50000,100000)
constexpr int E_     = 640000;
constexpr int D_     = 128;
constexpr int CAP_   = 64;       // bucket capacity; max degree ~38 (Poisson 12.8)
constexpr int NTILE  = (N_SRC_ + 31) / 32;   // 1563 src row-tiles
constexpr int MMB    = (NTILE + 3) / 4;      // 391 (fallback mm grid)

typedef float f32x4  __attribute__((ext_vector_type(4)));
typedef short bf16x8 __attribute__((ext_vector_type(8)));

union U4 { unsigned int u[4]; bf16x8 v; };

static __device__ __forceinline__ unsigned short f2bf_rne(float f) {
    unsigned int x = __float_as_uint(f);
    return (unsigned short)((x + 0x7FFFu + ((x >> 16) & 1u)) >> 16);
}

// ===========================================================================
// THE FUSED COOPERATIVE KERNEL
// ===========================================================================
__global__ __launch_bounds__(256, 4) void k_fused(
    const float* __restrict__ src, const float* __restrict__ dstf,
    const int* __restrict__ src_idx, const int* __restrict__ dst_idx,
    const float* __restrict__ W, const float* __restrict__ a,
    float* __restrict__ s, int* __restrict__ cursor,
    uint4* __restrict__ bucket, unsigned int* __restrict__ h,
    float* __restrict__ out)
{
    cg::grid_group grid = cg::this_grid();
    __shared__ unsigned short wl[128 * 128];   // 32 KB; s-role aliases first 4KB
    const int t  = threadIdx.x;
    const int NB = (int)gridDim.x;
    const int SB = NB >> 1;                    // s-role blocks [0,SB)

    // ---------------- Phase A ----------------
    if ((int)blockIdx.x < SB) {
        // s-role: cursor clear + va = W@a + s-dots
        float* val = (float*)wl;
        for (int cid = blockIdx.x * 256 + t; cid < N_DST_; cid += SB * 256)
            cursor[cid] = 0;
#pragma unroll
        for (int j = 0; j < 4; ++j) {
            int pair = t * 4 + j;             // 0..1023
            int k = pair >> 3, col = pair & 7;
            int half = col >> 2, hd = col & 3;
            float acc = 0.f;
            for (int c2 = 0; c2 < 32; ++c2)
                acc += W[(size_t)k * 128 + hd * 32 + c2] * a[half * 32 + c2];
            val[k * 8 + col] = acc;
        }
        __syncthreads();

        const int lane = t & 63;
        const int l32 = lane & 31, hf = lane >> 5;
        float4 vs[4], vd[4];
#pragma unroll
        for (int j = 0; j < 4; ++j) {
            vs[j] = *(const float4*)&val[(4 * l32 + j) * 8];
            vd[j] = *(const float4*)&val[(4 * l32 + j) * 8 + 4];
        }
        const int gw = (blockIdx.x * 256 + t) >> 6;
        const int stride = SB * 4;
        for (int p = gw; p < N_TOT_ / 2; p += stride) {
            int node = p * 2 + hf;
            bool is_src = node < N_SRC_;
            const float* f = is_src ? src + (size_t)node * D_
                                    : dstf + (size_t)(node - N_SRC_) * D_;
            float4 x = *(const float4*)(f + l32 * 4);
            float4 v0 = is_src ? vs[0] : vd[0];
            float4 v1 = is_src ? vs[1] : vd[1];
            float4 v2 = is_src ? vs[2] : vd[2];
            float4 v3 = is_src ? vs[3] : vd[3];
            float a0 = x.x * v0.x + x.y * v1.x + x.z * v2.x + x.w * v3.x;
            float a1 = x.x * v0.y + x.y * v1.y + x.z * v2.y + x.w * v3.y;
            float a2 = x.x * v0.z + x.y * v1.z + x.z * v2.z + x.w * v3.z;
            float a3 = x.x * v0.w + x.y * v1.w + x.z * v2.w + x.w * v3.w;
#pragma unroll
            for (int m = 1; m < 32; m <<= 1) {
                a0 += __shfl_xor(a0, m, 64);
                a1 += __shfl_xor(a1, m, 64);
                a2 += __shfl_xor(a2, m, 64);
                a3 += __shfl_xor(a3, m, 64);
            }
            if (l32 == 0)
                *(float4*)&s[(size_t)node * 4] = make_float4(a0, a1, a2, a3);
        }
    } else {
        // mm-role: stage W (bf16 + swizzle) then h = src_feat @ W
        {
            const int n = t >> 1, half = t & 1;
#pragma unroll
            for (int c8 = 0; c8 < 8; ++c8) {
                int c = half * 8 + c8;
                U4 P;
#pragma unroll
                for (int q = 0; q < 4; ++q) {
                    float f0 = W[(size_t)(c * 8 + 2 * q) * 128 + n];
                    float f1 = W[(size_t)(c * 8 + 2 * q + 1) * 128 + n];
                    P.u[q] = (unsigned int)f2bf_rne(f0)
                           | ((unsigned int)f2bf_rne(f1) << 16);
                }
                int slot = c ^ (n & 15);
                *(bf16x8*)&wl[n * 128 + slot * 8] = P.v;
            }
        }
        __syncthreads();

        const int wid = t >> 6, lane = t & 63;
        const int g = lane >> 4, sidx = lane & 15;
        for (int wtile = ((int)blockIdx.x - SB) * 4 + wid; wtile < NTILE;
             wtile += (NB - SB) * 4) {
            const int base = wtile * 32;
            const int r0 = base + sidx;                  // always < N_SRC_
            const int r1g = base + 16 + sidx;
            const int r1 = (r1g < N_SRC_) ? r1g : 0;     // clamp; stores guarded
            const float* p0 = src + (size_t)r0 * D_;
            const float* p1 = src + (size_t)r1 * D_;

            f32x4 acc[2][8];
#pragma unroll
            for (int m = 0; m < 2; ++m)
#pragma unroll
                for (int nf = 0; nf < 8; ++nf) acc[m][nf] = (f32x4)0.f;

#pragma unroll
            for (int ks = 0; ks < 4; ++ks) {
                const int k0 = ks * 32 + g * 8;
                bf16x8 af[2];
#pragma unroll
                for (int m = 0; m < 2; ++m) {
                    const float* p = m ? p1 : p0;
                    float4 v0 = *(const float4*)(p + k0);
                    float4 v1 = *(const float4*)(p + k0 + 4);
                    float f[8] = {v0.x, v0.y, v0.z, v0.w, v1.x, v1.y, v1.z, v1.w};
                    U4 P;
#pragma unroll
                    for (int q = 0; q < 4; ++q)
                        P.u[q] = (unsigned int)f2bf_rne(f[2 * q])
                               | ((unsigned int)f2bf_rne(f[2 * q + 1]) << 16);
                    af[m] = P.v;
                }
#pragma unroll
                for (int nf = 0; nf < 8; ++nf) {
                    const int n = nf * 16 + sidx;
                    const int off = n * 128 + ((ks * 4 + g) ^ sidx) * 8;
                    bf16x8 b = *(const bf16x8*)&wl[off];
                    acc[0][nf] = __builtin_amdgcn_mfma_f32_16x16x32_bf16(af[0], b, acc[0][nf], 0, 0, 0);
                    acc[1][nf] = __builtin_amdgcn_mfma_f32_16x16x32_bf16(af[1], b, acc[1][nf], 0, 0, 0);
                }
            }
#pragma unroll
            for (int m = 0; m < 2; ++m) {
                const int rowb = base + m * 16 + g * 4;
#pragma unroll
                for (int r = 0; r < 4; ++r) {
                    const int row = rowb + r;
                    if (row < N_SRC_) {
#pragma unroll
                        for (int q = 0; q < 4; ++q) {
                            unsigned int val2 = (unsigned int)f2bf_rne(acc[m][2 * q][r])
                                             | ((unsigned int)f2bf_rne(acc[m][2 * q + 1][r]) << 16);
                            h[(size_t)row * 64 + q * 16 + sidx] = val2;
                        }
                    }
                }
            }
        }
    }

    grid.sync();

    // ---------------- Phase B: scatter (all blocks) ----------------
    for (int e = blockIdx.x * 256 + t; e < E_; e += NB * 256) {
        int sn = src_idx[e], dn = dst_idx[e];
        float4 vsv = *(const float4*)&s[(size_t)sn * 4];
        float4 vdv = *(const float4*)&s[(size_t)(N_SRC_ + dn) * 4];
        float x0 = vsv.x + vdv.x, x1 = vsv.y + vdv.y;
        float x2 = vsv.z + vdv.z, x3 = vsv.w + vdv.w;
        float w0 = __expf(x0 > 0.f ? x0 : (__expf(x0) - 1.f));   // exp(elu(x))
        float w1 = __expf(x1 > 0.f ? x1 : (__expf(x1) - 1.f));
        float w2 = __expf(x2 > 0.f ? x2 : (__expf(x2) - 1.f));
        float w3 = __expf(x3 > 0.f ? x3 : (__expf(x3) - 1.f));
        uint4 ent;
        ent.x = (unsigned int)sn;
        ent.y = (unsigned int)f2bf_rne(w0) | ((unsigned int)f2bf_rne(w1) << 16);
        ent.z = (unsigned int)f2bf_rne(w2) | ((unsigned int)f2bf_rne(w3) << 16);
        ent.w = 0u;
        int pos = atomicAdd(&cursor[dn], 1);
        if (pos < CAP_) bucket[(size_t)dn * CAP_ + pos] = ent;
    }

    grid.sync();

    // ---------------- Phase C: gather (all blocks) ----------------
    {
        const int lane = t & 63;
        const int hd = lane >> 4, sub = lane & 15;
        for (int wid = (blockIdx.x * 256 + t) >> 6; wid < N_DST_; wid += NB * 4) {
            int cnt = min(cursor[wid], CAP_);
            const uint4* B = bucket + (size_t)wid * CAP_;
            auto wext = [&](const uint4& e) {
                unsigned int u = (hd & 2) ? e.z : e.y;
                return __uint_as_float((hd & 1) ? (u & 0xFFFF0000u) : (u << 16));
            };
            float2 A[4] = {make_float2(0.f, 0.f), make_float2(0.f, 0.f),
                           make_float2(0.f, 0.f), make_float2(0.f, 0.f)};
            float dacc[4] = {0.f, 0.f, 0.f, 0.f};
            int i = 0;
            for (; i + 8 <= cnt; i += 8) {
                uint4 e[8];
                unsigned int v[8];
#pragma unroll
                for (int j = 0; j < 8; ++j) e[j] = B[i + j];
#pragma unroll
                for (int j = 0; j < 8; ++j) v[j] = h[(size_t)e[j].x * 64 + lane];
#pragma unroll
                for (int j = 0; j < 8; ++j) {
                    float w = wext(e[j]);
                    dacc[j & 3] += w;
                    A[j & 3].x = fmaf(w, __uint_as_float(v[j] << 16), A[j & 3].x);
                    A[j & 3].y = fmaf(w, __uint_as_float(v[j] & 0xFFFF0000u), A[j & 3].y);
                }
            }
            for (; i + 4 <= cnt; i += 4) {
                uint4 e[4];
                unsigned int v[4];
#pragma unroll
                for (int j = 0; j < 4; ++j) e[j] = B[i + j];
#pragma unroll
                for (int j = 0; j < 4; ++j) v[j] = h[(size_t)e[j].x * 64 + lane];
#pragma unroll
                for (int j = 0; j < 4; ++j) {
                    float w = wext(e[j]);
                    dacc[j] += w;
                    A[j].x = fmaf(w, __uint_as_float(v[j] << 16), A[j].x);
                    A[j].y = fmaf(w, __uint_as_float(v[j] & 0xFFFF0000u), A[j].y);
                }
            }
            for (; i < cnt; ++i) {
                uint4 e = B[i];
                unsigned int v = h[(size_t)e.x * 64 + lane];
                float w = wext(e);
                dacc[0] += w;
                A[0].x = fmaf(w, __uint_as_float(v << 16), A[0].x);
                A[0].y = fmaf(w, __uint_as_float(v & 0xFFFF0000u), A[0].y);
            }
            float den = (dacc[0] + dacc[1]) + (dacc[2] + dacc[3]);
            float2 acc = make_float2((A[0].x + A[1].x) + (A[2].x + A[3].x),
                                     (A[0].y + A[1].y) + (A[2].y + A[3].y));
            float inv = 1.f / (den + 1e-12f);
            out[(size_t)wid * D_ + 32 * hd + sub]      = acc.x * inv;
            out[(size_t)wid * D_ + 32 * hd + sub + 16] = acc.y * inv;
        }
    }
}

// ===========================================================================
// FALLBACK PATH (round-10 kernels, verbatim) — used only if coop launch fails
// ===========================================================================
__global__ __launch_bounds__(256) void k_s2v(
    const float* __restrict__ src, const float* __restrict__ dst,
    const float* __restrict__ W, const float* __restrict__ a,
    float* __restrict__ s, int* __restrict__ cursor)
{
    __shared__ float val[128 * 8];
    const int t = threadIdx.x;
    int cid = blockIdx.x * 256 + t;
    if (cid < N_DST_) cursor[cid] = 0;
#pragma unroll
    for (int j = 0; j < 4; ++j) {
        int pair = t * 4 + j;
        int k = pair >> 3, col = pair & 7;
        int half = col >> 2, hd = col & 3;
        float acc = 0.f;
        for (int c2 = 0; c2 < 32; ++c2)
            acc += W[(size_t)k * 128 + hd * 32 + c2] * a[half * 32 + c2];
        val[k * 8 + col] = acc;
    }
    __syncthreads();
    const int gw = (blockIdx.x * 256 + t) >> 6;
    const int lane = t & 63;
    const int l32 = lane & 31, hf = lane >> 5;
    float4 vs[4], vd[4];
#pragma unroll
    for (int j = 0; j < 4; ++j) {
        vs[j] = *(const float4*)&val[(4 * l32 + j) * 8];
        vd[j] = *(const float4*)&val[(4 * l32 + j) * 8 + 4];
    }
    for (int p = gw; p < N_TOT_ / 2; p += 2048) {
        int node = p * 2 + hf;
        bool is_src = node < N_SRC_;
        const float* f = is_src ? src + (size_t)node * D_
                                : dst + (size_t)(node - N_SRC_) * D_;
        float4 x = *(const float4*)(f + l32 * 4);
        float4 v0 = is_src ? vs[0] : vd[0];
        float4 v1 = is_src ? vs[1] : vd[1];
        float4 v2 = is_src ? vs[2] : vd[2];
        float4 v3 = is_src ? vs[3] : vd[3];
        float a0 = x.x * v0.x + x.y * v1.x + x.z * v2.x + x.w * v3.x;
        float a1 = x.x * v0.y + x.y * v1.y + x.z * v2.y + x.w * v3.y;
        float a2 = x.x * v0.z + x.y * v1.z + x.z * v2.z + x.w * v3.z;
        float a3 = x.x * v0.w + x.y * v1.w + x.z * v2.w + x.w * v3.w;
#pragma unroll
        for (int m = 1; m < 32; m <<= 1) {
            a0 += __shfl_xor(a0, m, 64);
            a1 += __shfl_xor(a1, m, 64);
            a2 += __shfl_xor(a2, m, 64);
            a3 += __shfl_xor(a3, m, 64);
        }
        if (l32 == 0)
            *(float4*)&s[(size_t)node * 4] = make_float4(a0, a1, a2, a3);
    }
}

__global__ __launch_bounds__(256) void k_mm(
    const float* __restrict__ src, const float* __restrict__ W,
    unsigned int* __restrict__ h)
{
    __shared__ unsigned short wl[128 * 128];
    const int t = threadIdx.x;
    {
        const int n = t >> 1, half = t & 1;
#pragma unroll
        for (int c8 = 0; c8 < 8; ++c8) {
            int c = half * 8 + c8;
            U4 P;
#pragma unroll
            for (int q = 0; q < 4; ++q) {
                float f0 = W[(size_t)(c * 8 + 2 * q) * 128 + n];
                float f1 = W[(size_t)(c * 8 + 2 * q + 1) * 128 + n];
                P.u[q] = (unsigned int)f2bf_rne(f0)
                       | ((unsigned int)f2bf_rne(f1) << 16);
            }
            int slot = c ^ (n & 15);
            *(bf16x8*)&wl[n * 128 + slot * 8] = P.v;
        }
    }
    __syncthreads();
    const int wid = t >> 6, lane = t & 63;
    const int g = lane >> 4, sidx = lane & 15;
    const int wtile = blockIdx.x * 4 + wid;
    if (wtile >= NTILE) return;
    const int base = wtile * 32;
    const int r0 = base + sidx;
    const int r1g = base + 16 + sidx;
    const int r1 = (r1g < N_SRC_) ? r1g : 0;
    const float* p0 = src + (size_t)r0 * D_;
    const float* p1 = src + (size_t)r1 * D_;
    f32x4 acc[2][8];
#pragma unroll
    for (int m = 0; m < 2; ++m)
#pragma unroll
        for (int nf = 0; nf < 8; ++nf) acc[m][nf] = (f32x4)0.f;
#pragma unroll
    for (int ks = 0; ks < 4; ++ks) {
        const int k0 = ks * 32 + g * 8;
        bf16x8 af[2];
#pragma unroll
        for (int m = 0; m < 2; ++m) {
            const float* p = m ? p1 : p0;
            float4 v0 = *(const float4*)(p + k0);
            float4 v1 = *(const float4*)(p + k0 + 4);
            float f[8] = {v0.x, v0.y, v0.z, v0.w, v1.x, v1.y, v1.z, v1.w};
            U4 P;
#pragma unroll
            for (int q = 0; q < 4; ++q)
                P.u[q] = (unsigned int)f2bf_rne(f[2 * q])
                       | ((unsigned int)f2bf_rne(f[2 * q + 1]) << 16);
            af[m] = P.v;
        }
#pragma unroll
        for (int nf = 0; nf < 8; ++nf) {
            const int n = nf * 16 + sidx;
            const int off = n * 128 + ((ks * 4 + g) ^ sidx) * 8;
            bf16x8 b = *(const bf16x8*)&wl[off];
            acc[0][nf] = __builtin_amdgcn_mfma_f32_16x16x32_bf16(af[0], b, acc[0][nf], 0, 0, 0);
            acc[1][nf] = __builtin_amdgcn_mfma_f32_16x16x32_bf16(af[1], b, acc[1][nf], 0, 0, 0);
        }
    }
#pragma unroll
    for (int m = 0; m < 2; ++m) {
        const int rowb = base + m * 16 + g * 4;
#pragma unroll
        for (int r = 0; r < 4; ++r) {
            const int row = rowb + r;
            if (row < N_SRC_) {
#pragma unroll
                for (int q = 0; q < 4; ++q) {
                    unsigned int val = (unsigned int)f2bf_rne(acc[m][2 * q][r])
                                     | ((unsigned int)f2bf_rne(acc[m][2 * q + 1][r]) << 16);
                    h[(size_t)row * 64 + q * 16 + sidx] = val;
                }
            }
        }
    }
}

__global__ __launch_bounds__(256) void k_scatter(
    const int* __restrict__ src_idx, const int* __restrict__ dst_idx,
    const float* __restrict__ s,
    int* __restrict__ cursor, uint4* __restrict__ bucket)
{
    int e = blockIdx.x * 256 + threadIdx.x;
    int sn = src_idx[e], dn = dst_idx[e];
    float4 vsv = *(const float4*)&s[(size_t)sn * 4];
    float4 vdv = *(const float4*)&s[(size_t)(N_SRC_ + dn) * 4];
    float x0 = vsv.x + vdv.x, x1 = vsv.y + vdv.y;
    float x2 = vsv.z + vdv.z, x3 = vsv.w + vdv.w;
    float w0 = __expf(x0 > 0.f ? x0 : (__expf(x0) - 1.f));
    float w1 = __expf(x1 > 0.f ? x1 : (__expf(x1) - 1.f));
    float w2 = __expf(x2 > 0.f ? x2 : (__expf(x2) - 1.f));
    float w3 = __expf(x3 > 0.f ? x3 : (__expf(x3) - 1.f));
    uint4 ent;
    ent.x = (unsigned int)sn;
    ent.y = (unsigned int)f2bf_rne(w0) | ((unsigned int)f2bf_rne(w1) << 16);
    ent.z = (unsigned int)f2bf_rne(w2) | ((unsigned int)f2bf_rne(w3) << 16);
    ent.w = 0u;
    int pos = atomicAdd(&cursor[dn], 1);
    if (pos < CAP_) bucket[(size_t)dn * CAP_ + pos] = ent;
}

__global__ __launch_bounds__(256) void k_gather(
    const unsigned int* __restrict__ h2, const int* __restrict__ cursor,
    const uint4* __restrict__ bucket, float* __restrict__ out)
{
    int wid = (blockIdx.x * 256 + threadIdx.x) >> 6;
    int lane = threadIdx.x & 63;
    if (wid >= N_DST_) return;
    int cnt = min(cursor[wid], CAP_);
    const int hd = lane >> 4;
    const int sub = lane & 15;
    const uint4* B = bucket + (size_t)wid * CAP_;
    auto wext = [&](const uint4& e) {
        unsigned int u = (hd & 2) ? e.z : e.y;
        return __uint_as_float((hd & 1) ? (u & 0xFFFF0000u) : (u << 16));
    };
    float2 A[4] = {make_float2(0.f, 0.f), make_float2(0.f, 0.f),
                   make_float2(0.f, 0.f), make_float2(0.f, 0.f)};
    float dacc[4] = {0.f, 0.f, 0.f, 0.f};
    int i = 0;
    for (; i + 8 <= cnt; i += 8) {
        uint4 e[8];
        unsigned int v[8];
#pragma unroll
        for (int j = 0; j < 8; ++j) e[j] = B[i + j];
#pragma unroll
        for (int j = 0; j < 8; ++j) v[j] = h2[(size_t)e[j].x * 64 + lane];
#pragma unroll
        for (int j = 0; j < 8; ++j) {
            float w = wext(e[j]);
            dacc[j & 3] += w;
            A[j & 3].x = fmaf(w, __uint_as_float(v[j] << 16), A[j & 3].x);
            A[j & 3].y = fmaf(w, __uint_as_float(v[j] & 0xFFFF0000u), A[j & 3].y);
        }
    }
    for (; i + 4 <= cnt; i += 4) {
        uint4 e[4];
        unsigned int v[4];
#pragma unroll
        for (int j = 0; j < 4; ++j) e[j] = B[i + j];
#pragma unroll
        for (int j = 0; j < 4; ++j) v[j] = h2[(size_t)e[j].x * 64 + lane];
#pragma unroll
        for (int j = 0; j < 4; ++j) {
            float w = wext(e[j]);
            dacc[j] += w;
            A[j].x = fmaf(w, __uint_as_float(v[j] << 16), A[j].x);
            A[j].y = fmaf(w, __uint_as_float(v[j] & 0xFFFF0000u), A[j].y);
        }
    }
    for (; i < cnt; ++i) {
        uint4 e = B[i];
        unsigned int v = h2[(size_t)e.x * 64 + lane];
        float w = wext(e);
        dacc[0] += w;
        A[0].x = fmaf(w, __uint_as_float(v << 16), A[0].x);
        A[0].y = fmaf(w, __uint_as_float(v & 0xFFFF0000u), A[0].y);
    }
    float den = (dacc[0] + dacc[1]) + (dacc[2] + dacc[3]);
    float2 acc = make_float2((A[0].x + A[1].x) + (A[2].x + A[3].x),
                             (A[0].y + A[1].y) + (A[2].y + A[3].y));
    float inv = 1.f / (den + 1e-12f);
    out[(size_t)wid * D_ + 32 * hd + sub]      = acc.x * inv;
    out[(size_t)wid * D_ + 32 * hd + sub + 16] = acc.y * inv;
}

// ---------------------------------------------------------------------------
extern "C" void kernel_launch(void* const* d_in, const int* in_sizes, int n_in,
                              void* d_out, int out_size, void* d_ws, size_t ws_size,
                              hipStream_t stream)
{
    const float* src_feat = (const float*)d_in[0];
    const float* dst_feat = (const float*)d_in[1];
    const int*   edge     = (const int*)d_in[2];   // [2, E]
    const int*   src_idx  = edge;
    const int*   dst_idx  = edge + E_;
    const float* W        = (const float*)d_in[3];
    const float* a        = (const float*)d_in[4];
    float*       out      = (float*)d_out;

    char* p = (char*)d_ws;
    auto alloc = [&](size_t bytes) {
        char* r = p;
        p += (bytes + 255) & ~(size_t)255;
        return r;
    };
    unsigned int* h = (unsigned int*)alloc((size_t)N_SRC_ * 64 * 4);          // 12.8 MB
    float* s        = (float*)alloc((size_t)N_TOT_ * 4 * sizeof(float));      // 1.6 MB
    int*   cursor   = (int*)alloc((size_t)N_DST_ * sizeof(int));              // 0.2 MB
    uint4* bucket   = (uint4*)alloc((size_t)N_DST_ * CAP_ * sizeof(uint4));   // 51.2 MB

    // Cooperative grid sizing: __launch_bounds__(256,4) guarantees >=4 blk/CU
    // (VGPR<=128, LDS 32KB<=40KB); clamp via occupancy query for safety.
    int perCU = 0;
    hipError_t qerr = hipOccupancyMaxActiveBlocksPerMultiprocessor(
        &perCU, (const void*)k_fused, 256, 0);
    int NB = (qerr == hipSuccess && perCU > 0) ? perCU * 256 : 1024;
    if (NB > 1024) NB = 1024;
    NB &= ~1;                      // even, for the half/half role split
    if (NB < 2) NB = 2;

    void* args[] = {(void*)&src_feat, (void*)&dst_feat, (void*)&src_idx,
                    (void*)&dst_idx, (void*)&W, (void*)&a, (void*)&s,
                    (void*)&cursor, (void*)&bucket, (void*)&h, (void*)&out};
    hipError_t err = hipLaunchCooperativeKernel(
        (const void*)k_fused, dim3(NB), dim3(256), args, 0, stream);

    if (err != hipSuccess) {
        // Fallback: proven round-10 4-dispatch path.
        k_s2v<<<512, 256, 0, stream>>>(src_feat, dst_feat, W, a, s, cursor);
        k_mm<<<MMB, 256, 0, stream>>>(src_feat, W, h);
        k_scatter<<<E_ / 256, 256, 0, stream>>>(src_idx, dst_idx, s, cursor, bucket);
        k_gather<<<(N_DST_ * 64 + 255) / 256, 256, 0, stream>>>(
            h, cursor, bucket, out);
    }
}